// Round 9
// baseline (600.992 us; speedup 1.0000x reference)
//
#include <hip/hip_runtime.h>
#include <hip/hip_bf16.h>

// MHSA_69621419869026 — p=4 sketch linear attention, MI355X gfx950.
// Round 15 (base = r13, 390us best; r14 wide-tile REVERTED — VGPR 156 killed
// occupancy 20->11%):
//  * both MFMA GEMMs: LDS ELIMINATED. Per-lane direct global loads of MFMA
//    fragments (A row-major panels are XCD-exclusive + j-consecutive slots
//    co-resident -> A served from L2 ~20x reuse; WTf/WTp fully L2-resident).
//    Removes: 51us/CU ds_read floor, 1.05e7 conflict cycles, ALL barriers
//    (independent waves), staging VALU. Register pipeline depth 1 with two
//    named fragment sets (rule #20: no runtime indexing), full unroll ->
//    offset immediates on 8 base pointers. T5 setprio kept.
//  * prep_all / kv_mfma / kv_reduce / attn_mfma unchanged (r13).
// Dims: B=4 S=8192 D=512 H=8 HD=R=64, N=B*S=32768.

#define SEQ 8192

typedef __attribute__((ext_vector_type(8))) short bf16x8;
typedef __attribute__((ext_vector_type(4))) float f32x4;

__device__ __forceinline__ unsigned short f2b(float f) {
    union { float f; unsigned int i; } v; v.f = f;
    unsigned int r = v.i + 0x7fffu + ((v.i >> 16) & 1u);   // RNE
    return (unsigned short)(r >> 16);
}
__device__ __forceinline__ float b2f(unsigned short u) {
    union { unsigned int i; float f; } v; v.i = ((unsigned int)u) << 16; return v.f;
}

// ---------------- merged pre-pass --------------------------------------------
// blocks [0,8192): convert_x;  [8192,8704): convert_wT;  [8704,9217): wc + bv.
__global__ __launch_bounds__(256) void prep_all(
    const float* __restrict__ x, unsigned short* __restrict__ xb,
    const float* __restrict__ Wv, const float* __restrict__ Wp,
    unsigned short* __restrict__ WTf, unsigned short* __restrict__ WTp,
    const float* __restrict__ Wq, const float* __restrict__ bq,
    const float* __restrict__ Wk, const float* __restrict__ bk,
    const float* __restrict__ bv,
    const float* __restrict__ gq, const float* __restrict__ bbq,
    const float* __restrict__ gk, const float* __restrict__ bbk,
    const float* __restrict__ qG1, const float* __restrict__ qG2,
    const float* __restrict__ kG1, const float* __restrict__ kG2,
    float* __restrict__ cvec)
{
    const int blk = blockIdx.x;
    const int tid = threadIdx.x;

    if (blk < 8192) {                       // ---- convert_x ----
        size_t i = ((size_t)blk * 256 + tid) * 8;
        float4 a = *(const float4*)&x[i];
        float4 b = *(const float4*)&x[i + 4];
        ushort4 o1 = { f2b(a.x), f2b(a.y), f2b(a.z), f2b(a.w) };
        ushort4 o2 = { f2b(b.x), f2b(b.y), f2b(b.z), f2b(b.w) };
        *(ushort4*)&xb[i]     = o1;
        *(ushort4*)&xb[i + 4] = o2;
        return;
    }

    if (blk < 8704) {                       // ---- convert_wT ----
        const int idx = blk - 8192;
        const int z = idx >> 8;
        const float* W = (z == 0) ? Wv : Wp;
        unsigned short* O = (z == 0) ? (WTf + (size_t)2048 * 512) : WTp;
        __shared__ float t[32][33];
        const int tx = tid & 31, ty = tid >> 5;
        const int k0 = ((idx >> 4) & 15) * 32, n0 = (idx & 15) * 32;
        #pragma unroll
        for (int i = 0; i < 4; ++i)
            t[ty + 8 * i][tx] = W[(size_t)(k0 + ty + 8 * i) * 512 + n0 + tx];
        __syncthreads();
        #pragma unroll
        for (int i = 0; i < 4; ++i)
            O[(size_t)(n0 + ty + 8 * i) * 512 + k0 + tx] = f2b(t[tx][ty + 8 * i]);
        return;
    }

    // ---- precompute_wc ----
    const int idx = blk - 8704;
    if (idx == 512) {
        for (int i = tid; i < 512; i += 256) cvec[2048 + i] = bv[i];
        return;
    }
    const int bi = idx & 31, ky = idx >> 5;
    const int zz = bi >> 4, h = (bi >> 1) & 7, p = bi & 1;
    const float* W    = zz ? Wk : Wq;
    const float* bias = zz ? bk : bq;
    const float* G    = zz ? (p ? kG2 : kG1) : (p ? qG2 : qG1);
    const float  gamma = zz ? gk[0] : gq[0];
    const float  beta  = zz ? bbk[0] : bbq[0];

    __shared__ float Gs[64][65];
    for (int i = tid; i < 4096; i += 256) Gs[i >> 6][i & 63] = G[i];
    __syncthreads();

    const int rr = tid & 63, kg = tid >> 6;
    const int jc = zz * 1024 + h * 128 + rr * 2 + p;
    const int k0 = ky * 32;
    for (int k = k0 + kg; k < k0 + 32; k += 4) {
        float s = 0.f;
        const float* wrow = &W[(size_t)k * 512 + h * 64];
        #pragma unroll 8
        for (int j = 0; j < 64; ++j) s = fmaf(wrow[j], Gs[j][rr], s);
        WTf[(size_t)jc * 512 + k] = f2b(gamma * s);
    }
    if (kg == 0 && ky == 0) {
        float cb = 0.f, cg = 0.f;
        #pragma unroll 8
        for (int j = 0; j < 64; ++j) {
            cb = fmaf(bias[h * 64 + j], Gs[j][rr], cb);
            cg += Gs[j][rr];
        }
        cvec[jc] = gamma * cb + beta * cg;
    }
}

// ---- LDS-free GEMM core macros ---------------------------------------------
// fragment loads: per-lane b128 from global (L2-served). 8 base ptrs, k-step
// advances by 32 shorts = 64B -> compile-time offset immediates after unroll.
#define LOADF(AF, BF, kk)                                                       \
    do {                                                                        \
        _Pragma("unroll")                                                       \
        for (int i = 0; i < 4; ++i) {                                           \
            AF[i] = *(const bf16x8*)(pA[i] + (kk));                             \
            BF[i] = *(const bf16x8*)(pB[i] + (kk));                             \
        }                                                                       \
    } while (0)

#define MFMA16(AF, BF)                                                          \
    do {                                                                        \
        __builtin_amdgcn_s_setprio(1);                                          \
        _Pragma("unroll")                                                       \
        for (int mi = 0; mi < 4; ++mi)                                          \
            _Pragma("unroll")                                                   \
            for (int ni = 0; ni < 4; ++ni)                                      \
                acc[mi][ni] = __builtin_amdgcn_mfma_f32_16x16x32_bf16(          \
                    AF[mi], BF[ni], acc[mi][ni], 0, 0, 0);                      \
        __builtin_amdgcn_s_setprio(0);                                          \
    } while (0)

// full K loop: 16 steps, depth-1 register pipeline, two named fragment sets.
#define KLOOP_REG                                                               \
    do {                                                                        \
        bf16x8 aX[4], bX[4], aY[4], bY[4];                                      \
        LOADF(aX, bX, 0);                                                       \
        _Pragma("unroll")                                                       \
        for (int t = 0; t < 16; t += 2) {                                       \
            if (t + 1 < 16) LOADF(aY, bY, (t + 1) * 32);                        \
            MFMA16(aX, bX);                                                     \
            if (t + 2 < 16) LOADF(aX, bX, (t + 2) * 32);                        \
            MFMA16(aY, bY);                                                     \
        }                                                                       \
    } while (0)

// ---------------- fused MFMA GEMM: U = x @ WC, phi/v epilogue ----------------
// grid 5120 flat, XCD swizzle (xcd = flat&7 owns 32 exclusive token panels,
// j fastest within panel -> A panel L2-resident across its 20 j-blocks).
// 128x128 tile, 4 waves, NO LDS, NO barriers.
__global__ __launch_bounds__(256) void gemm_mfma_fused(
    const unsigned short* __restrict__ xb,
    const unsigned short* __restrict__ WTf,
    const float* __restrict__ cvec,
    unsigned short* __restrict__ PHIQ, unsigned short* __restrict__ PHIKT,
    unsigned short* __restrict__ VT)
{
    const int tid = threadIdx.x;
    const int w = tid >> 6, lane = tid & 63;
    const int flat = blockIdx.x;
    const int xcd = flat & 7, slot = flat >> 3;      // 640 slots per XCD
    const int n0 = (xcd * 32 + slot / 20) * 128;     // token panel (exclusive)
    const int j0 = (slot % 20) * 128;                // j tile
    const int wr = w >> 1, wc = w & 1;

    const int rm = lane & 15;
    const int kq = (lane >> 4) * 8;

    const unsigned short* pA[4];
    const unsigned short* pB[4];
    #pragma unroll
    for (int i = 0; i < 4; ++i) {
        pA[i] = &xb [(size_t)(n0 + wr * 64 + i * 16 + rm) * 512 + kq];
        pB[i] = &WTf[(size_t)(j0 + wc * 64 + i * 16 + rm) * 512 + kq];
    }

    f32x4 acc[4][4];
    #pragma unroll
    for (int i = 0; i < 4; ++i)
        #pragma unroll
        for (int j = 0; j < 4; ++j) { acc[i][j] = (f32x4){0.f, 0.f, 0.f, 0.f}; }

    KLOOP_REG;

    // ---------------- epilogue (j0 block-uniform), direct stores ------------
    const int bq = n0 >> 13;                  // batch
    const int sq = n0 & (SEQ - 1);            // first s of tile
    const int t0 = sq + wr * 64 + (lane >> 4) * 4;   // + mi*16 per mi

    if (j0 < 2048) {                          // phi paths (q or k)
        const int zq = j0 >> 10;              // 0 = q, 1 = k (block-uniform)
        const int h  = (j0 >> 7) & 7;
        #pragma unroll
        for (int ni = 0; ni < 4; ++ni) {
            const int loc = wc * 64 + ni * 16 + (lane & 15);
            const float cv = cvec[j0 + loc];
            const int rr = loc >> 1;
            #pragma unroll
            for (int mi = 0; mi < 4; ++mi) {
                float ph[4];
                #pragma unroll
                for (int r = 0; r < 4; ++r) {
                    float u = acc[mi][ni][r] + cv;
                    float up = __shfl_xor(u, 1);
                    float hh = 0.125f * u * up;
                    ph[r] = hh * hh;
                }
                if ((lane & 1) == 0) {
                    if (zq == 0) {
                        #pragma unroll
                        for (int r = 0; r < 4; ++r)
                            PHIQ[((size_t)(bq * 8 + h) * SEQ + t0 + mi * 16 + r) * 64 + rr]
                                = f2b(ph[r]);
                    } else {
                        ushort4 o = { f2b(ph[0]), f2b(ph[1]), f2b(ph[2]), f2b(ph[3]) };
                        *(ushort4*)&PHIKT[((size_t)((bq * 8 + h) * 64 + rr)) * SEQ
                                          + t0 + mi * 16] = o;
                    }
                }
            }
        }
    } else {                                  // v path -> VT[b, n, s]
        #pragma unroll
        for (int ni = 0; ni < 4; ++ni) {
            const int loc = wc * 64 + ni * 16 + (lane & 15);
            const int n = (j0 - 2048) + loc;
            const float cv = cvec[j0 + loc];
            #pragma unroll
            for (int mi = 0; mi < 4; ++mi) {
                ushort4 o = { f2b(acc[mi][ni][0] + cv), f2b(acc[mi][ni][1] + cv),
                              f2b(acc[mi][ni][2] + cv), f2b(acc[mi][ni][3] + cv) };
                *(ushort4*)&VT[((size_t)(bq * 512 + n)) * SEQ + t0 + mi * 16] = o;
            }
        }
    }
}

// ---------------- bf16 MFMA GEMM: final projection ---------------------------
// grid 1024 flat; XCD swizzle; same LDS-free register-pipelined core.
__global__ __launch_bounds__(256) void gemm_mfma_final(
    const unsigned short* __restrict__ Ab,
    const unsigned short* __restrict__ WTp,
    const float* __restrict__ bias, float* __restrict__ out)
{
    const int tid = threadIdx.x;
    const int w = tid >> 6, lane = tid & 63;
    const int flat = blockIdx.x;
    const int xcd = flat & 7, slot = flat >> 3;      // 128 slots per XCD
    const int n0 = (xcd * 32 + (slot >> 2)) * 128;
    const int j0 = (slot & 3) * 128;
    const int wr = w >> 1, wc = w & 1;

    const int rm = lane & 15;
    const int kq = (lane >> 4) * 8;

    const unsigned short* pA[4];
    const unsigned short* pB[4];
    #pragma unroll
    for (int i = 0; i < 4; ++i) {
        pA[i] = &Ab [(size_t)(n0 + wr * 64 + i * 16 + rm) * 512 + kq];
        pB[i] = &WTp[(size_t)(j0 + wc * 64 + i * 16 + rm) * 512 + kq];
    }

    f32x4 acc[4][4];
    #pragma unroll
    for (int i = 0; i < 4; ++i)
        #pragma unroll
        for (int j = 0; j < 4; ++j) { acc[i][j] = (f32x4){0.f, 0.f, 0.f, 0.f}; }

    KLOOP_REG;

    #pragma unroll
    for (int ni = 0; ni < 4; ++ni) {
        const int jcol = j0 + wc * 64 + ni * 16 + (lane & 15);
        const float bvv = bias[jcol];
        #pragma unroll
        for (int mi = 0; mi < 4; ++mi) {
            #pragma unroll
            for (int r = 0; r < 4; ++r) {
                const int t = n0 + wr * 64 + mi * 16 + (lane >> 4) * 4 + r;
                out[(size_t)t * 512 + jcol] = acc[mi][ni][r] + bvv;
            }
        }
    }
}

// ---------------- kv = phi_k^T @ v via MFMA, split-K over 32 segments --------
__global__ __launch_bounds__(256) void kv_mfma(
    const unsigned short* __restrict__ PHIKT, const unsigned short* __restrict__ VT,
    float* __restrict__ KVP, float* __restrict__ KSP)
{
    const int bh = blockIdx.x, seg = blockIdx.y;
    const int tid = threadIdx.x;
    const int w = tid >> 6, lane = tid & 63;
    const size_t pbase =
        ((size_t)bh * 64 + w * 16 + (lane & 15)) * SEQ + seg * 256 + (lane >> 4) * 8;
    const size_t vbase =
        ((size_t)((bh >> 3) * 512 + (bh & 7) * 64 + (lane & 15))) * SEQ
        + seg * 256 + (lane >> 4) * 8;

    f32x4 acc[4], ks;
    #pragma unroll
    for (int nt = 0; nt < 4; ++nt) acc[nt] = (f32x4){0.f, 0.f, 0.f, 0.f};
    ks = (f32x4){0.f, 0.f, 0.f, 0.f};
    bf16x8 ones;
    #pragma unroll
    for (int i = 0; i < 8; ++i) ones[i] = (short)0x3f80;   // bf16 1.0

    #pragma unroll 2
    for (int k = 0; k < 256; k += 32) {
        bf16x8 a = *(const bf16x8*)&PHIKT[pbase + k];
        ks = __builtin_amdgcn_mfma_f32_16x16x32_bf16(a, ones, ks, 0, 0, 0);
        #pragma unroll
        for (int nt = 0; nt < 4; ++nt) {
            bf16x8 bb = *(const bf16x8*)&VT[vbase + (size_t)nt * 16 * SEQ + k];
            acc[nt] = __builtin_amdgcn_mfma_f32_16x16x32_bf16(a, bb, acc[nt], 0, 0, 0);
        }
    }

    float* kvp = &KVP[((size_t)bh * 32 + seg) * 4096];
    #pragma unroll
    for (int nt = 0; nt < 4; ++nt) {
        float4 o = { acc[nt][0], acc[nt][1], acc[nt][2], acc[nt][3] };
        *(float4*)&kvp[(nt * 16 + (lane & 15)) * 64 + w * 16 + (lane >> 4) * 4] = o;
    }
    if ((lane & 15) == 0) {
        float4 o = { ks[0], ks[1], ks[2], ks[3] };
        *(float4*)&KSP[((size_t)bh * 32 + seg) * 64 + w * 16 + (lane >> 4) * 4] = o;
    }
}

__global__ __launch_bounds__(256) void kv_reduce(
    const float* __restrict__ KVP, const float* __restrict__ KSP,
    float* __restrict__ KV, float* __restrict__ KS)
{
    const int bh = blockIdx.x;
    const int e0 = blockIdx.y * 512;
    for (int e = e0 + threadIdx.x; e < e0 + 512; e += 256) {
        float s = 0.f;
        #pragma unroll 8
        for (int c = 0; c < 32; ++c) s += KVP[(size_t)(bh * 32 + c) * 4096 + e];
        KV[(size_t)bh * 4096 + e] = s;
    }
    if (blockIdx.y == 0 && threadIdx.x < 64) {
        float s = 0.f;
        for (int c = 0; c < 32; ++c) s += KSP[(bh * 32 + c) * 64 + threadIdx.x];
        KS[bh * 64 + threadIdx.x] = s;
    }
}

// ---------------- out_attn = (phi_q@KV)/(phi_q@ksum+eps) via MFMA ------------
__global__ __launch_bounds__(256) void attn_mfma(
    const unsigned short* __restrict__ PHIQ, const float* __restrict__ KV,
    const float* __restrict__ KS, unsigned short* __restrict__ OAb)
{
    __shared__ __align__(16) unsigned short bpad[144 * 72];
    const int bh = blockIdx.x, st = blockIdx.y;
    const int tid = threadIdx.x;
    const int b = bh >> 3, h = bh & 7;

    for (int i = tid; i < 144 * 64; i += 256) {
        const int n = i >> 6, r = i & 63;
        float val;
        if (n < 64)        val = KV[(size_t)bh * 4096 + n * 64 + r];
        else if (n < 128)  { float x = KV[(size_t)bh * 4096 + (n - 64) * 64 + r];
                             val = x - b2f(f2b(x)); }
        else if (n == 128) val = KS[bh * 64 + r];
        else if (n == 129) { float x = KS[bh * 64 + r]; val = x - b2f(f2b(x)); }
        else               val = 0.f;
        bpad[n * 72 + r] = f2b(val);
    }
    __syncthreads();

    const int w = tid >> 6, lane = tid & 63;
    bf16x8 bf[9][2];
    #pragma unroll
    for (int nt = 0; nt < 9; ++nt) {
        const unsigned short* bp = &bpad[(nt * 16 + (lane & 15)) * 72 + (lane >> 4) * 8];
        bf[nt][0] = *(const bf16x8*)bp;
        bf[nt][1] = *(const bf16x8*)(bp + 32);
    }

    const int tw = st * 256 + w * 64;
    #pragma unroll
    for (int mt = 0; mt < 4; ++mt) {
        const unsigned short* ap =
            &PHIQ[((size_t)bh * SEQ + tw + mt * 16 + (lane & 15)) * 64 + (lane >> 4) * 8];
        bf16x8 a0 = *(const bf16x8*)ap;
        bf16x8 a1 = *(const bf16x8*)(ap + 32);
        f32x4 acc[9];
        #pragma unroll
        for (int nt = 0; nt < 9; ++nt) acc[nt] = (f32x4){0.f, 0.f, 0.f, 0.f};
        #pragma unroll
        for (int nt = 0; nt < 9; ++nt) {
            acc[nt] = __builtin_amdgcn_mfma_f32_16x16x32_bf16(a0, bf[nt][0], acc[nt], 0, 0, 0);
            acc[nt] = __builtin_amdgcn_mfma_f32_16x16x32_bf16(a1, bf[nt][1], acc[nt], 0, 0, 0);
        }
        #pragma unroll
        for (int r4 = 0; r4 < 4; ++r4) {
            const float den = __shfl(acc[8][r4], (lane & 48)) +
                              __shfl(acc[8][r4], (lane & 48) + 1) + 1e-6f;
            const float inv = 1.0f / den;
            const int s = tw + mt * 16 + (lane >> 4) * 4 + r4;
            #pragma unroll
            for (int nt = 0; nt < 4; ++nt)
                OAb[((size_t)b * SEQ + s) * 512 + h * 64 + nt * 16 + (lane & 15)] =
                    f2b((acc[nt][r4] + acc[nt + 4][r4]) * inv);
        }
    }
}

extern "C" void kernel_launch(void* const* d_in, const int* in_sizes, int n_in,
                              void* d_out, int out_size, void* d_ws, size_t ws_size,
                              hipStream_t stream)
{
    (void)in_sizes; (void)n_in; (void)out_size; (void)ws_size;
    const float* x   = (const float*)d_in[0];
    const float* Wq  = (const float*)d_in[1];
    const float* bq  = (const float*)d_in[2];
    const float* Wk  = (const float*)d_in[3];
    const float* bk  = (const float*)d_in[4];
    const float* Wv  = (const float*)d_in[5];
    const float* bv  = (const float*)d_in[6];
    const float* Wp  = (const float*)d_in[7];
    const float* bp  = (const float*)d_in[8];
    const float* gq  = (const float*)d_in[9];
    const float* bbq = (const float*)d_in[10];
    const float* gk  = (const float*)d_in[11];
    const float* bbk = (const float*)d_in[12];
    const float* qG1 = (const float*)d_in[13];
    const float* qG2 = (const float*)d_in[14];
    const float* kG1 = (const float*)d_in[15];
    const float* kG2 = (const float*)d_in[16];

    unsigned short* PHIQ  = (unsigned short*)d_ws;      // 32 MB [b,h,s,r]
    unsigned short* PHIKT = PHIQ + 16777216;            // 32 MB [b,h,r,s]
    unsigned short* VT    = PHIKT + 16777216;           // 32 MB [b,h*64+d,s]
    unsigned short* xb    = VT   + 16777216;            // 32 MB
    unsigned short* OAb   = xb   + 16777216;            // 32 MB
    unsigned short* WTf   = OAb  + 16777216;            // 2.5 MB
    unsigned short* WTp   = WTf  + 2560 * 512;          // 0.5 MB
    float* cvec = (float*)(WTp + 262144);               // 2,560 f
    float* KVP  = cvec + 2560;                          // 16 MB [bh,seg32][d][r]
    float* KSP  = KVP + 4194304;                        // 256 KB
    float* KV   = KSP + 65536;                          // 512 KB [bh][d][r]
    float* KS   = KV + 131072;                          // 8 KB
    float* out  = (float*)d_out;

    hipLaunchKernelGGL(prep_all, dim3(9217), dim3(256), 0, stream,
                       x, xb, Wv, Wp, WTf, WTp,
                       Wq, bq, Wk, bk, bv, gq, bbq, gk, bbk,
                       qG1, qG2, kG1, kG2, cvec);
    hipLaunchKernelGGL(gemm_mfma_fused, dim3(5120), dim3(256), 0, stream,
                       xb, WTf, cvec, PHIQ, PHIKT, VT);
    hipLaunchKernelGGL(kv_mfma, dim3(32, 32), dim3(256), 0, stream,
                       PHIKT, VT, KVP, KSP);
    hipLaunchKernelGGL(kv_reduce, dim3(32, 8), dim3(256), 0, stream, KVP, KSP, KV, KS);
    hipLaunchKernelGGL(attn_mfma, dim3(32, 32), dim3(256), 0, stream,
                       PHIQ, KV, KS, OAb);
    hipLaunchKernelGGL(gemm_mfma_final, dim3(1024), dim3(256), 0, stream,
                       OAb, WTp, bp, out);
}

// Round 10
// 392.761 us; speedup vs baseline: 1.5302x; 1.5302x over previous
//
#include <hip/hip_runtime.h>
#include <hip/hip_bf16.h>

// MHSA_69621419869026 — p=4 sketch linear attention, MI355X gfx950.
// Round 16 = r13 (best verified: 390us, fused 147us) + CORRECT 16B-chunk
// XOR swizzle on both GEMMs' LDS fragment path:
//   read pattern was 8-way bank conflict (rows stride 16 banks; only
//   (row>>1)&3 distinguishes bank groups — r8's row&3 formula was wrong).
//   chunk ^= (row>>1)&3 -> exactly 2 lanes/bank-group = free (m136).
//   Both-sides (rule #21): pre-swizzled per-lane GLOBAL source for
//   global_load_lds (LDS dest stays linear) + swizzled ds_read offset.
//   (row+16)>>1 &3 == (row>>1)&3, so one source formula serves both cp16s.
// r15 (LDS-free direct-global) REVERTED: 328us, MfmaUtil 10.6% — VMEM pipe
// at L2 latency is far slower than the LDS path.
// Dims: B=4 S=8192 D=512 H=8 HD=R=64, N=B*S=32768.

#define SEQ 8192

typedef __attribute__((ext_vector_type(8))) short bf16x8;
typedef __attribute__((ext_vector_type(4))) float f32x4;

__device__ __forceinline__ unsigned short f2b(float f) {
    union { float f; unsigned int i; } v; v.f = f;
    unsigned int r = v.i + 0x7fffu + ((v.i >> 16) & 1u);   // RNE
    return (unsigned short)(r >> 16);
}
__device__ __forceinline__ float b2f(unsigned short u) {
    union { unsigned int i; float f; } v; v.i = ((unsigned int)u) << 16; return v.f;
}

#if __has_builtin(__builtin_amdgcn_global_load_lds)
#define ASYNC_CP 1
#endif

__device__ __forceinline__ void cp16(const unsigned short* g, unsigned short* l) {
#ifdef ASYNC_CP
    __builtin_amdgcn_global_load_lds(
        (const __attribute__((address_space(1))) unsigned int*)g,
        (__attribute__((address_space(3))) unsigned int*)l, 16, 0, 0);
#endif
}

// raw barrier / counted waits: opaque to the compiler waitcnt pass (no
// auto-inserted vmcnt(0) drain); "memory" clobber keeps ordering correct.
#define SBAR      asm volatile("s_barrier" ::: "memory")
#define WAITV(n)  asm volatile("s_waitcnt vmcnt(" #n ")" ::: "memory")

// ---------------- merged pre-pass --------------------------------------------
// blocks [0,8192): convert_x;  [8192,8704): convert_wT;  [8704,9217): wc + bv.
__global__ __launch_bounds__(256) void prep_all(
    const float* __restrict__ x, unsigned short* __restrict__ xb,
    const float* __restrict__ Wv, const float* __restrict__ Wp,
    unsigned short* __restrict__ WTf, unsigned short* __restrict__ WTp,
    const float* __restrict__ Wq, const float* __restrict__ bq,
    const float* __restrict__ Wk, const float* __restrict__ bk,
    const float* __restrict__ bv,
    const float* __restrict__ gq, const float* __restrict__ bbq,
    const float* __restrict__ gk, const float* __restrict__ bbk,
    const float* __restrict__ qG1, const float* __restrict__ qG2,
    const float* __restrict__ kG1, const float* __restrict__ kG2,
    float* __restrict__ cvec)
{
    const int blk = blockIdx.x;
    const int tid = threadIdx.x;

    if (blk < 8192) {                       // ---- convert_x ----
        size_t i = ((size_t)blk * 256 + tid) * 8;
        float4 a = *(const float4*)&x[i];
        float4 b = *(const float4*)&x[i + 4];
        ushort4 o1 = { f2b(a.x), f2b(a.y), f2b(a.z), f2b(a.w) };
        ushort4 o2 = { f2b(b.x), f2b(b.y), f2b(b.z), f2b(b.w) };
        *(ushort4*)&xb[i]     = o1;
        *(ushort4*)&xb[i + 4] = o2;
        return;
    }

    if (blk < 8704) {                       // ---- convert_wT ----
        const int idx = blk - 8192;
        const int z = idx >> 8;
        const float* W = (z == 0) ? Wv : Wp;
        unsigned short* O = (z == 0) ? (WTf + (size_t)2048 * 512) : WTp;
        __shared__ float t[32][33];
        const int tx = tid & 31, ty = tid >> 5;
        const int k0 = ((idx >> 4) & 15) * 32, n0 = (idx & 15) * 32;
        #pragma unroll
        for (int i = 0; i < 4; ++i)
            t[ty + 8 * i][tx] = W[(size_t)(k0 + ty + 8 * i) * 512 + n0 + tx];
        __syncthreads();
        #pragma unroll
        for (int i = 0; i < 4; ++i)
            O[(size_t)(n0 + ty + 8 * i) * 512 + k0 + tx] = f2b(t[tx][ty + 8 * i]);
        return;
    }

    // ---- precompute_wc ----
    const int idx = blk - 8704;
    if (idx == 512) {
        for (int i = tid; i < 512; i += 256) cvec[2048 + i] = bv[i];
        return;
    }
    const int bi = idx & 31, ky = idx >> 5;
    const int zz = bi >> 4, h = (bi >> 1) & 7, p = bi & 1;
    const float* W    = zz ? Wk : Wq;
    const float* bias = zz ? bk : bq;
    const float* G    = zz ? (p ? kG2 : kG1) : (p ? qG2 : qG1);
    const float  gamma = zz ? gk[0] : gq[0];
    const float  beta  = zz ? bbk[0] : bbq[0];

    __shared__ float Gs[64][65];
    for (int i = tid; i < 4096; i += 256) Gs[i >> 6][i & 63] = G[i];
    __syncthreads();

    const int rr = tid & 63, kg = tid >> 6;
    const int jc = zz * 1024 + h * 128 + rr * 2 + p;
    const int k0 = ky * 32;
    for (int k = k0 + kg; k < k0 + 32; k += 4) {
        float s = 0.f;
        const float* wrow = &W[(size_t)k * 512 + h * 64];
        #pragma unroll 8
        for (int j = 0; j < 64; ++j) s = fmaf(wrow[j], Gs[j][rr], s);
        WTf[(size_t)jc * 512 + k] = f2b(gamma * s);
    }
    if (kg == 0 && ky == 0) {
        float cb = 0.f, cg = 0.f;
        #pragma unroll 8
        for (int j = 0; j < 64; ++j) {
            cb = fmaf(bias[h * 64 + j], Gs[j][rr], cb);
            cg += Gs[j][rr];
        }
        cvec[jc] = gamma * cb + beta * cg;
    }
}

// ---- pipelined-GEMM shared macros (r13 structure + T2 swizzle) --------------
// smem layout: 3 buffers x [A 4096 | B 4096] shorts (48 KB total).
// Each stage = 4 global_load_lds per wave. LDS dest LINEAR; global source
// pre-swizzled (kq below) so LDS slot (row, c) holds global chunk
// c ^ ((row>>1)&3). Reads apply the same XOR -> 2-way (free) bank pattern.
#define STAGE_P(kk, off)                                                        \
    do {                                                                        \
        unsigned short* dA = sm + (off) + (w * 32) * 32;                        \
        cp16(gA + (kk), dA);                                                    \
        cp16(gA + 16 * 512 + (kk), dA + 16 * 32);                               \
        unsigned short* dB = sm + (off) + 4096 + (w * 32) * 32;                 \
        cp16(gB + (kk), dB);                                                    \
        cp16(gB + 16 * 512 + (kk), dB + 16 * 32);                               \
    } while (0)

#define COMPUTE_P(off)                                                          \
    do {                                                                        \
        bf16x8 af[4], bfr[4];                                                   \
        _Pragma("unroll")                                                       \
        for (int i = 0; i < 4; ++i) {                                           \
            af[i]  = *(const bf16x8*)&sm[(off) + (wr * 64 + i * 16 + (lane & 15)) * 32 + cr]; \
            bfr[i] = *(const bf16x8*)&sm[(off) + 4096 + (wc * 64 + i * 16 + (lane & 15)) * 32 + cr]; \
        }                                                                       \
        __builtin_amdgcn_s_setprio(1);                                          \
        _Pragma("unroll")                                                       \
        for (int mi = 0; mi < 4; ++mi)                                          \
            _Pragma("unroll")                                                   \
            for (int ni = 0; ni < 4; ++ni)                                      \
                acc[mi][ni] = __builtin_amdgcn_mfma_f32_16x16x32_bf16(          \
                    af[mi], bfr[ni], acc[mi][ni], 0, 0, 0);                     \
        __builtin_amdgcn_s_setprio(0);                                          \
    } while (0)

// K-loop: 16 steps, depth-2 prefetch, counted vmcnt (8 steady / 4 / 0 tail).
#define KLOOP_P                                                                 \
    do {                                                                        \
        STAGE_P(0, 0u);                                                         \
        STAGE_P(32, 8192u);                                                     \
        unsigned o0 = 0u, o1 = 8192u, o2 = 16384u;                              \
        _Pragma("unroll 1")                                                     \
        for (int t = 0; t < 16; ++t) {                                          \
            SBAR;                          /* all waves done with buf o2 */     \
            if (t < 14) {                                                       \
                STAGE_P((t + 2) * 32, o2);                                      \
                WAITV(8);                  /* stage(t) landed (this wave) */     \
            } else if (t == 14) {                                               \
                WAITV(4);                                                       \
            } else {                                                            \
                WAITV(0);                                                       \
            }                                                                   \
            SBAR;                          /* stage(t) landed (all waves) */     \
            COMPUTE_P(o0);                                                      \
            unsigned tmp = o0; o0 = o1; o1 = o2; o2 = tmp;                      \
        }                                                                       \
    } while (0)

// ---------------- fused MFMA GEMM: U = x @ WC, phi/v epilogue ----------------
// grid 5120 flat, XCD swizzle (xcd = flat&7 owns 32 exclusive token panels).
// 128x128 tile, 4 waves. T4 pipelined K-loop (48 KB LDS) + T2 read swizzle.
__global__ __launch_bounds__(256) void gemm_mfma_fused(
    const unsigned short* __restrict__ xb,
    const unsigned short* __restrict__ WTf,
    const float* __restrict__ cvec,
    unsigned short* __restrict__ PHIQ, unsigned short* __restrict__ PHIKT,
    unsigned short* __restrict__ VT)
{
    __shared__ __align__(16) unsigned short smem[24576];   // 48 KB
    unsigned short* sm = smem;

    const int tid = threadIdx.x;
    const int w = tid >> 6, lane = tid & 63;
    const int flat = blockIdx.x;
    const int xcd = flat & 7, slot = flat >> 3;      // 640 slots per XCD
    const int n0 = (xcd * 32 + slot / 20) * 128;     // token panel (exclusive)
    const int j0 = (slot % 20) * 128;                // j tile
    const int wr = w >> 1, wc = w & 1;

    const int r0 = w * 32 + (lane >> 2);
    // staging source pre-swizzle: LDS slot (row = lane>>2 (+16), c = lane&3)
    // must hold global chunk c ^ ((row>>1)&3) = (lane&3) ^ ((lane>>3)&3).
    // ((row+16)>>1)&3 == (row>>1)&3, so the same formula serves both cp16s.
    const int kq = ((lane & 3) ^ ((lane >> 3) & 3)) * 8;
    const unsigned short* gA = &xb[(size_t)(n0 + r0) * 512 + kq];
    const unsigned short* gB = &WTf[(size_t)(j0 + r0) * 512 + kq];

    f32x4 acc[4][4];
    #pragma unroll
    for (int i = 0; i < 4; ++i)
        #pragma unroll
        for (int j = 0; j < 4; ++j) { acc[i][j] = (f32x4){0.f, 0.f, 0.f, 0.f}; }

    // read-side: fragment row = wr*64 + i*16 + (lane&15); (row>>1)&3 =
    // ((lane&15)>>1)&3 = (lane>>1)&3 (wave/i terms vanish mod 4).
    const int cr = (((lane >> 4) ^ ((lane >> 1) & 3)) * 8);

    KLOOP_P;

    // ---------------- epilogue (j0 block-uniform), direct stores ------------
    const int bq = n0 >> 13;                  // batch
    const int sq = n0 & (SEQ - 1);            // first s of tile
    const int t0 = sq + wr * 64 + (lane >> 4) * 4;   // + mi*16 per mi

    if (j0 < 2048) {                          // phi paths (q or k)
        const int zq = j0 >> 10;              // 0 = q, 1 = k (block-uniform)
        const int h  = (j0 >> 7) & 7;
        #pragma unroll
        for (int ni = 0; ni < 4; ++ni) {
            const int loc = wc * 64 + ni * 16 + (lane & 15);
            const float cv = cvec[j0 + loc];
            const int rr = loc >> 1;
            #pragma unroll
            for (int mi = 0; mi < 4; ++mi) {
                float ph[4];
                #pragma unroll
                for (int r = 0; r < 4; ++r) {
                    float u = acc[mi][ni][r] + cv;
                    float up = __shfl_xor(u, 1);
                    float hh = 0.125f * u * up;
                    ph[r] = hh * hh;
                }
                if ((lane & 1) == 0) {
                    if (zq == 0) {
                        #pragma unroll
                        for (int r = 0; r < 4; ++r)
                            PHIQ[((size_t)(bq * 8 + h) * SEQ + t0 + mi * 16 + r) * 64 + rr]
                                = f2b(ph[r]);
                    } else {
                        ushort4 o = { f2b(ph[0]), f2b(ph[1]), f2b(ph[2]), f2b(ph[3]) };
                        *(ushort4*)&PHIKT[((size_t)((bq * 8 + h) * 64 + rr)) * SEQ
                                          + t0 + mi * 16] = o;
                    }
                }
            }
        }
    } else {                                  // v path -> VT[b, n, s]
        #pragma unroll
        for (int ni = 0; ni < 4; ++ni) {
            const int loc = wc * 64 + ni * 16 + (lane & 15);
            const int n = (j0 - 2048) + loc;
            const float cv = cvec[j0 + loc];
            #pragma unroll
            for (int mi = 0; mi < 4; ++mi) {
                ushort4 o = { f2b(acc[mi][ni][0] + cv), f2b(acc[mi][ni][1] + cv),
                              f2b(acc[mi][ni][2] + cv), f2b(acc[mi][ni][3] + cv) };
                *(ushort4*)&VT[((size_t)(bq * 512 + n)) * SEQ + t0 + mi * 16] = o;
            }
        }
    }
}

// ---------------- bf16 MFMA GEMM: final projection ---------------------------
// grid 1024 flat; XCD swizzle; T4 pipelined K-loop + T2 swizzle.
__global__ __launch_bounds__(256) void gemm_mfma_final(
    const unsigned short* __restrict__ Ab,
    const unsigned short* __restrict__ WTp,
    const float* __restrict__ bias, float* __restrict__ out)
{
    __shared__ __align__(16) unsigned short smem[24576];   // 48 KB
    unsigned short* sm = smem;

    const int tid = threadIdx.x;
    const int w = tid >> 6, lane = tid & 63;
    const int flat = blockIdx.x;
    const int xcd = flat & 7, slot = flat >> 3;      // 128 slots per XCD
    const int n0 = (xcd * 32 + (slot >> 2)) * 128;
    const int j0 = (slot & 3) * 128;
    const int wr = w >> 1, wc = w & 1;

    const int r0 = w * 32 + (lane >> 2);
    const int kq = ((lane & 3) ^ ((lane >> 3) & 3)) * 8;
    const unsigned short* gA = &Ab[(size_t)(n0 + r0) * 512 + kq];
    const unsigned short* gB = &WTp[(size_t)(j0 + r0) * 512 + kq];

    f32x4 acc[4][4];
    #pragma unroll
    for (int i = 0; i < 4; ++i)
        #pragma unroll
        for (int j = 0; j < 4; ++j) { acc[i][j] = (f32x4){0.f, 0.f, 0.f, 0.f}; }

    const int cr = (((lane >> 4) ^ ((lane >> 1) & 3)) * 8);

    KLOOP_P;

    #pragma unroll
    for (int ni = 0; ni < 4; ++ni) {
        const int jcol = j0 + wc * 64 + ni * 16 + (lane & 15);
        const float bvv = bias[jcol];
        #pragma unroll
        for (int mi = 0; mi < 4; ++mi) {
            #pragma unroll
            for (int r = 0; r < 4; ++r) {
                const int t = n0 + wr * 64 + mi * 16 + (lane >> 4) * 4 + r;
                out[(size_t)t * 512 + jcol] = acc[mi][ni][r] + bvv;
            }
        }
    }
}

// ---------------- kv = phi_k^T @ v via MFMA, split-K over 32 segments --------
__global__ __launch_bounds__(256) void kv_mfma(
    const unsigned short* __restrict__ PHIKT, const unsigned short* __restrict__ VT,
    float* __restrict__ KVP, float* __restrict__ KSP)
{
    const int bh = blockIdx.x, seg = blockIdx.y;
    const int tid = threadIdx.x;
    const int w = tid >> 6, lane = tid & 63;
    const size_t pbase =
        ((size_t)bh * 64 + w * 16 + (lane & 15)) * SEQ + seg * 256 + (lane >> 4) * 8;
    const size_t vbase =
        ((size_t)((bh >> 3) * 512 + (bh & 7) * 64 + (lane & 15))) * SEQ
        + seg * 256 + (lane >> 4) * 8;

    f32x4 acc[4], ks;
    #pragma unroll
    for (int nt = 0; nt < 4; ++nt) acc[nt] = (f32x4){0.f, 0.f, 0.f, 0.f};
    ks = (f32x4){0.f, 0.f, 0.f, 0.f};
    bf16x8 ones;
    #pragma unroll
    for (int i = 0; i < 8; ++i) ones[i] = (short)0x3f80;   // bf16 1.0

    #pragma unroll 2
    for (int k = 0; k < 256; k += 32) {
        bf16x8 a = *(const bf16x8*)&PHIKT[pbase + k];
        ks = __builtin_amdgcn_mfma_f32_16x16x32_bf16(a, ones, ks, 0, 0, 0);
        #pragma unroll
        for (int nt = 0; nt < 4; ++nt) {
            bf16x8 bb = *(const bf16x8*)&VT[vbase + (size_t)nt * 16 * SEQ + k];
            acc[nt] = __builtin_amdgcn_mfma_f32_16x16x32_bf16(a, bb, acc[nt], 0, 0, 0);
        }
    }

    float* kvp = &KVP[((size_t)bh * 32 + seg) * 4096];
    #pragma unroll
    for (int nt = 0; nt < 4; ++nt) {
        float4 o = { acc[nt][0], acc[nt][1], acc[nt][2], acc[nt][3] };
        *(float4*)&kvp[(nt * 16 + (lane & 15)) * 64 + w * 16 + (lane >> 4) * 4] = o;
    }
    if ((lane & 15) == 0) {
        float4 o = { ks[0], ks[1], ks[2], ks[3] };
        *(float4*)&KSP[((size_t)bh * 32 + seg) * 64 + w * 16 + (lane >> 4) * 4] = o;
    }
}

__global__ __launch_bounds__(256) void kv_reduce(
    const float* __restrict__ KVP, const float* __restrict__ KSP,
    float* __restrict__ KV, float* __restrict__ KS)
{
    const int bh = blockIdx.x;
    const int e0 = blockIdx.y * 512;
    for (int e = e0 + threadIdx.x; e < e0 + 512; e += 256) {
        float s = 0.f;
        #pragma unroll 8
        for (int c = 0; c < 32; ++c) s += KVP[(size_t)(bh * 32 + c) * 4096 + e];
        KV[(size_t)bh * 4096 + e] = s;
    }
    if (blockIdx.y == 0 && threadIdx.x < 64) {
        float s = 0.f;
        for (int c = 0; c < 32; ++c) s += KSP[(bh * 32 + c) * 64 + threadIdx.x];
        KS[bh * 64 + threadIdx.x] = s;
    }
}

// ---------------- out_attn = (phi_q@KV)/(phi_q@ksum+eps) via MFMA ------------
__global__ __launch_bounds__(256) void attn_mfma(
    const unsigned short* __restrict__ PHIQ, const float* __restrict__ KV,
    const float* __restrict__ KS, unsigned short* __restrict__ OAb)
{
    __shared__ __align__(16) unsigned short bpad[144 * 72];
    const int bh = blockIdx.x, st = blockIdx.y;
    const int tid = threadIdx.x;
    const int b = bh >> 3, h = bh & 7;

    for (int i = tid; i < 144 * 64; i += 256) {
        const int n = i >> 6, r = i & 63;
        float val;
        if (n < 64)        val = KV[(size_t)bh * 4096 + n * 64 + r];
        else if (n < 128)  { float x = KV[(size_t)bh * 4096 + (n - 64) * 64 + r];
                             val = x - b2f(f2b(x)); }
        else if (n == 128) val = KS[bh * 64 + r];
        else if (n == 129) { float x = KS[bh * 64 + r]; val = x - b2f(f2b(x)); }
        else               val = 0.f;
        bpad[n * 72 + r] = f2b(val);
    }
    __syncthreads();

    const int w = tid >> 6, lane = tid & 63;
    bf16x8 bf[9][2];
    #pragma unroll
    for (int nt = 0; nt < 9; ++nt) {
        const unsigned short* bp = &bpad[(nt * 16 + (lane & 15)) * 72 + (lane >> 4) * 8];
        bf[nt][0] = *(const bf16x8*)bp;
        bf[nt][1] = *(const bf16x8*)(bp + 32);
    }

    const int tw = st * 256 + w * 64;
    #pragma unroll
    for (int mt = 0; mt < 4; ++mt) {
        const unsigned short* ap =
            &PHIQ[((size_t)bh * SEQ + tw + mt * 16 + (lane & 15)) * 64 + (lane >> 4) * 8];
        bf16x8 a0 = *(const bf16x8*)ap;
        bf16x8 a1 = *(const bf16x8*)(ap + 32);
        f32x4 acc[9];
        #pragma unroll
        for (int nt = 0; nt < 9; ++nt) acc[nt] = (f32x4){0.f, 0.f, 0.f, 0.f};
        #pragma unroll
        for (int nt = 0; nt < 9; ++nt) {
            acc[nt] = __builtin_amdgcn_mfma_f32_16x16x32_bf16(a0, bf[nt][0], acc[nt], 0, 0, 0);
            acc[nt] = __builtin_amdgcn_mfma_f32_16x16x32_bf16(a1, bf[nt][1], acc[nt], 0, 0, 0);
        }
        #pragma unroll
        for (int r4 = 0; r4 < 4; ++r4) {
            const float den = __shfl(acc[8][r4], (lane & 48)) +
                              __shfl(acc[8][r4], (lane & 48) + 1) + 1e-6f;
            const float inv = 1.0f / den;
            const int s = tw + mt * 16 + (lane >> 4) * 4 + r4;
            #pragma unroll
            for (int nt = 0; nt < 4; ++nt)
                OAb[((size_t)b * SEQ + s) * 512 + h * 64 + nt * 16 + (lane & 15)] =
                    f2b((acc[nt][r4] + acc[nt + 4][r4]) * inv);
        }
    }
}

extern "C" void kernel_launch(void* const* d_in, const int* in_sizes, int n_in,
                              void* d_out, int out_size, void* d_ws, size_t ws_size,
                              hipStream_t stream)
{
    (void)in_sizes; (void)n_in; (void)out_size; (void)ws_size;
    const float* x   = (const float*)d_in[0];
    const float* Wq  = (const float*)d_in[1];
    const float* bq  = (const float*)d_in[2];
    const float* Wk  = (const float*)d_in[3];
    const float* bk  = (const float*)d_in[4];
    const float* Wv  = (const float*)d_in[5];
    const float* bv  = (const float*)d_in[6];
    const float* Wp  = (const float*)d_in[7];
    const float* bp  = (const float*)d_in[8];
    const float* gq  = (const float*)d_in[9];
    const float* bbq = (const float*)d_in[10];
    const float* gk  = (const float*)d_in[11];
    const float* bbk = (const float*)d_in[12];
    const float* qG1 = (const float*)d_in[13];
    const float* qG2 = (const float*)d_in[14];
    const float* kG1 = (const float*)d_in[15];
    const float* kG2 = (const float*)d_in[16];

    unsigned short* PHIQ  = (unsigned short*)d_ws;      // 32 MB [b,h,s,r]
    unsigned short* PHIKT = PHIQ + 16777216;            // 32 MB [b,h,r,s]
    unsigned short* VT    = PHIKT + 16777216;           // 32 MB [b,h*64+d,s]
    unsigned short* xb    = VT   + 16777216;            // 32 MB
    unsigned short* OAb   = xb   + 16777216;            // 32 MB
    unsigned short* WTf   = OAb  + 16777216;            // 2.5 MB
    unsigned short* WTp   = WTf  + 2560 * 512;          // 0.5 MB
    float* cvec = (float*)(WTp + 262144);               // 2,560 f
    float* KVP  = cvec + 2560;                          // 16 MB [bh,seg32][d][r]
    float* KSP  = KVP + 4194304;                        // 256 KB
    float* KV   = KSP + 65536;                          // 512 KB [bh][d][r]
    float* KS   = KV + 131072;                          // 8 KB
    float* out  = (float*)d_out;

    hipLaunchKernelGGL(prep_all, dim3(9217), dim3(256), 0, stream,
                       x, xb, Wv, Wp, WTf, WTp,
                       Wq, bq, Wk, bk, bv, gq, bbq, gk, bbk,
                       qG1, qG2, kG1, kG2, cvec);
    hipLaunchKernelGGL(gemm_mfma_fused, dim3(5120), dim3(256), 0, stream,
                       xb, WTf, cvec, PHIQ, PHIKT, VT);
    hipLaunchKernelGGL(kv_mfma, dim3(32, 32), dim3(256), 0, stream,
                       PHIKT, VT, KVP, KSP);
    hipLaunchKernelGGL(kv_reduce, dim3(32, 8), dim3(256), 0, stream, KVP, KSP, KV, KS);
    hipLaunchKernelGGL(attn_mfma, dim3(32, 32), dim3(256), 0, stream,
                       PHIQ, KV, KS, OAb);
    hipLaunchKernelGGL(gemm_mfma_final, dim3(1024), dim3(256), 0, stream,
                       OAb, WTp, bp, out);
}

// Round 11
// 389.841 us; speedup vs baseline: 1.5416x; 1.0075x over previous
//
#include <hip/hip_runtime.h>
#include <hip/hip_bf16.h>

// MHSA_69621419869026 — p=4 sketch linear attention, MI355X gfx950.
// Round 17 (base = r16: 392.8us, fused 144.4us conflict-free):
//  * kv_mfma REWRITE: was 16-way-scattered global b128 fragment loads
//    (rows at 16KB stride -> 16 disjoint 64B requests per instr,
//    latency-bound). Now: coalesced global_load_lds staging (rows are
//    contiguous 512B -> 1KB per cp16), 3-buffer counted-vmcnt K-loop
//    (r13's proven shape, BK=64, 4 steps), both-sides XOR chunk swizzle
//    (r16's proven formula adapted to 128B rows) -> LDS reads at the
//    8-cycle structural floor.
//  * attn_mfma: OAb stores were 64x scattered 2B per wave. bpad LDS is
//    dead after fragment loads -> reuse as per-wave bounce; stores now
//    64B-coalesced uint4.
//  * gemm_mfma_fused / gemm_mfma_final / prep_all / kv_reduce unchanged.
// Dims: B=4 S=8192 D=512 H=8 HD=R=64, N=B*S=32768.

#define SEQ 8192

typedef __attribute__((ext_vector_type(8))) short bf16x8;
typedef __attribute__((ext_vector_type(4))) float f32x4;

__device__ __forceinline__ unsigned short f2b(float f) {
    union { float f; unsigned int i; } v; v.f = f;
    unsigned int r = v.i + 0x7fffu + ((v.i >> 16) & 1u);   // RNE
    return (unsigned short)(r >> 16);
}
__device__ __forceinline__ float b2f(unsigned short u) {
    union { unsigned int i; float f; } v; v.i = ((unsigned int)u) << 16; return v.f;
}

#if __has_builtin(__builtin_amdgcn_global_load_lds)
#define ASYNC_CP 1
#endif

__device__ __forceinline__ void cp16(const unsigned short* g, unsigned short* l) {
#ifdef ASYNC_CP
    __builtin_amdgcn_global_load_lds(
        (const __attribute__((address_space(1))) unsigned int*)g,
        (__attribute__((address_space(3))) unsigned int*)l, 16, 0, 0);
#endif
}

// raw barrier / counted waits: opaque to the compiler waitcnt pass (no
// auto-inserted vmcnt(0) drain); "memory" clobber keeps ordering correct.
#define SBAR      asm volatile("s_barrier" ::: "memory")
#define WAITV(n)  asm volatile("s_waitcnt vmcnt(" #n ")" ::: "memory")

// ---------------- merged pre-pass --------------------------------------------
// blocks [0,8192): convert_x;  [8192,8704): convert_wT;  [8704,9217): wc + bv.
__global__ __launch_bounds__(256) void prep_all(
    const float* __restrict__ x, unsigned short* __restrict__ xb,
    const float* __restrict__ Wv, const float* __restrict__ Wp,
    unsigned short* __restrict__ WTf, unsigned short* __restrict__ WTp,
    const float* __restrict__ Wq, const float* __restrict__ bq,
    const float* __restrict__ Wk, const float* __restrict__ bk,
    const float* __restrict__ bv,
    const float* __restrict__ gq, const float* __restrict__ bbq,
    const float* __restrict__ gk, const float* __restrict__ bbk,
    const float* __restrict__ qG1, const float* __restrict__ qG2,
    const float* __restrict__ kG1, const float* __restrict__ kG2,
    float* __restrict__ cvec)
{
    const int blk = blockIdx.x;
    const int tid = threadIdx.x;

    if (blk < 8192) {                       // ---- convert_x ----
        size_t i = ((size_t)blk * 256 + tid) * 8;
        float4 a = *(const float4*)&x[i];
        float4 b = *(const float4*)&x[i + 4];
        ushort4 o1 = { f2b(a.x), f2b(a.y), f2b(a.z), f2b(a.w) };
        ushort4 o2 = { f2b(b.x), f2b(b.y), f2b(b.z), f2b(b.w) };
        *(ushort4*)&xb[i]     = o1;
        *(ushort4*)&xb[i + 4] = o2;
        return;
    }

    if (blk < 8704) {                       // ---- convert_wT ----
        const int idx = blk - 8192;
        const int z = idx >> 8;
        const float* W = (z == 0) ? Wv : Wp;
        unsigned short* O = (z == 0) ? (WTf + (size_t)2048 * 512) : WTp;
        __shared__ float t[32][33];
        const int tx = tid & 31, ty = tid >> 5;
        const int k0 = ((idx >> 4) & 15) * 32, n0 = (idx & 15) * 32;
        #pragma unroll
        for (int i = 0; i < 4; ++i)
            t[ty + 8 * i][tx] = W[(size_t)(k0 + ty + 8 * i) * 512 + n0 + tx];
        __syncthreads();
        #pragma unroll
        for (int i = 0; i < 4; ++i)
            O[(size_t)(n0 + ty + 8 * i) * 512 + k0 + tx] = f2b(t[tx][ty + 8 * i]);
        return;
    }

    // ---- precompute_wc ----
    const int idx = blk - 8704;
    if (idx == 512) {
        for (int i = tid; i < 512; i += 256) cvec[2048 + i] = bv[i];
        return;
    }
    const int bi = idx & 31, ky = idx >> 5;
    const int zz = bi >> 4, h = (bi >> 1) & 7, p = bi & 1;
    const float* W    = zz ? Wk : Wq;
    const float* bias = zz ? bk : bq;
    const float* G    = zz ? (p ? kG2 : kG1) : (p ? qG2 : qG1);
    const float  gamma = zz ? gk[0] : gq[0];
    const float  beta  = zz ? bbk[0] : bbq[0];

    __shared__ float Gs[64][65];
    for (int i = tid; i < 4096; i += 256) Gs[i >> 6][i & 63] = G[i];
    __syncthreads();

    const int rr = tid & 63, kg = tid >> 6;
    const int jc = zz * 1024 + h * 128 + rr * 2 + p;
    const int k0 = ky * 32;
    for (int k = k0 + kg; k < k0 + 32; k += 4) {
        float s = 0.f;
        const float* wrow = &W[(size_t)k * 512 + h * 64];
        #pragma unroll 8
        for (int j = 0; j < 64; ++j) s = fmaf(wrow[j], Gs[j][rr], s);
        WTf[(size_t)jc * 512 + k] = f2b(gamma * s);
    }
    if (kg == 0 && ky == 0) {
        float cb = 0.f, cg = 0.f;
        #pragma unroll 8
        for (int j = 0; j < 64; ++j) {
            cb = fmaf(bias[h * 64 + j], Gs[j][rr], cb);
            cg += Gs[j][rr];
        }
        cvec[jc] = gamma * cb + beta * cg;
    }
}

// ---- pipelined-GEMM shared macros (r13 structure + T2 swizzle) --------------
#define STAGE_P(kk, off)                                                        \
    do {                                                                        \
        unsigned short* dA = sm + (off) + (w * 32) * 32;                        \
        cp16(gA + (kk), dA);                                                    \
        cp16(gA + 16 * 512 + (kk), dA + 16 * 32);                               \
        unsigned short* dB = sm + (off) + 4096 + (w * 32) * 32;                 \
        cp16(gB + (kk), dB);                                                    \
        cp16(gB + 16 * 512 + (kk), dB + 16 * 32);                               \
    } while (0)

#define COMPUTE_P(off)                                                          \
    do {                                                                        \
        bf16x8 af[4], bfr[4];                                                   \
        _Pragma("unroll")                                                       \
        for (int i = 0; i < 4; ++i) {                                           \
            af[i]  = *(const bf16x8*)&sm[(off) + (wr * 64 + i * 16 + (lane & 15)) * 32 + cr]; \
            bfr[i] = *(const bf16x8*)&sm[(off) + 4096 + (wc * 64 + i * 16 + (lane & 15)) * 32 + cr]; \
        }                                                                       \
        __builtin_amdgcn_s_setprio(1);                                          \
        _Pragma("unroll")                                                       \
        for (int mi = 0; mi < 4; ++mi)                                          \
            _Pragma("unroll")                                                   \
            for (int ni = 0; ni < 4; ++ni)                                      \
                acc[mi][ni] = __builtin_amdgcn_mfma_f32_16x16x32_bf16(          \
                    af[mi], bfr[ni], acc[mi][ni], 0, 0, 0);                     \
        __builtin_amdgcn_s_setprio(0);                                          \
    } while (0)

#define KLOOP_P                                                                 \
    do {                                                                        \
        STAGE_P(0, 0u);                                                         \
        STAGE_P(32, 8192u);                                                     \
        unsigned o0 = 0u, o1 = 8192u, o2 = 16384u;                              \
        _Pragma("unroll 1")                                                     \
        for (int t = 0; t < 16; ++t) {                                          \
            SBAR;                                                               \
            if (t < 14) {                                                       \
                STAGE_P((t + 2) * 32, o2);                                      \
                WAITV(8);                                                       \
            } else if (t == 14) {                                               \
                WAITV(4);                                                       \
            } else {                                                            \
                WAITV(0);                                                       \
            }                                                                   \
            SBAR;                                                               \
            COMPUTE_P(o0);                                                      \
            unsigned tmp = o0; o0 = o1; o1 = o2; o2 = tmp;                      \
        }                                                                       \
    } while (0)

// ---------------- fused MFMA GEMM: U = x @ WC, phi/v epilogue ----------------
// grid 5120 flat, XCD swizzle. 128x128 tile, 4 waves. T4 pipelined K-loop
// (48 KB LDS) + T2 read swizzle (conflict-free, r16).
__global__ __launch_bounds__(256) void gemm_mfma_fused(
    const unsigned short* __restrict__ xb,
    const unsigned short* __restrict__ WTf,
    const float* __restrict__ cvec,
    unsigned short* __restrict__ PHIQ, unsigned short* __restrict__ PHIKT,
    unsigned short* __restrict__ VT)
{
    __shared__ __align__(16) unsigned short smem[24576];   // 48 KB
    unsigned short* sm = smem;

    const int tid = threadIdx.x;
    const int w = tid >> 6, lane = tid & 63;
    const int flat = blockIdx.x;
    const int xcd = flat & 7, slot = flat >> 3;      // 640 slots per XCD
    const int n0 = (xcd * 32 + slot / 20) * 128;     // token panel (exclusive)
    const int j0 = (slot % 20) * 128;                // j tile
    const int wr = w >> 1, wc = w & 1;

    const int r0 = w * 32 + (lane >> 2);
    const int kq = ((lane & 3) ^ ((lane >> 3) & 3)) * 8;
    const unsigned short* gA = &xb[(size_t)(n0 + r0) * 512 + kq];
    const unsigned short* gB = &WTf[(size_t)(j0 + r0) * 512 + kq];

    f32x4 acc[4][4];
    #pragma unroll
    for (int i = 0; i < 4; ++i)
        #pragma unroll
        for (int j = 0; j < 4; ++j) { acc[i][j] = (f32x4){0.f, 0.f, 0.f, 0.f}; }

    const int cr = (((lane >> 4) ^ ((lane >> 1) & 3)) * 8);

    KLOOP_P;

    // ---------------- epilogue (j0 block-uniform), direct stores ------------
    const int bq = n0 >> 13;                  // batch
    const int sq = n0 & (SEQ - 1);            // first s of tile
    const int t0 = sq + wr * 64 + (lane >> 4) * 4;   // + mi*16 per mi

    if (j0 < 2048) {                          // phi paths (q or k)
        const int zq = j0 >> 10;              // 0 = q, 1 = k (block-uniform)
        const int h  = (j0 >> 7) & 7;
        #pragma unroll
        for (int ni = 0; ni < 4; ++ni) {
            const int loc = wc * 64 + ni * 16 + (lane & 15);
            const float cv = cvec[j0 + loc];
            const int rr = loc >> 1;
            #pragma unroll
            for (int mi = 0; mi < 4; ++mi) {
                float ph[4];
                #pragma unroll
                for (int r = 0; r < 4; ++r) {
                    float u = acc[mi][ni][r] + cv;
                    float up = __shfl_xor(u, 1);
                    float hh = 0.125f * u * up;
                    ph[r] = hh * hh;
                }
                if ((lane & 1) == 0) {
                    if (zq == 0) {
                        #pragma unroll
                        for (int r = 0; r < 4; ++r)
                            PHIQ[((size_t)(bq * 8 + h) * SEQ + t0 + mi * 16 + r) * 64 + rr]
                                = f2b(ph[r]);
                    } else {
                        ushort4 o = { f2b(ph[0]), f2b(ph[1]), f2b(ph[2]), f2b(ph[3]) };
                        *(ushort4*)&PHIKT[((size_t)((bq * 8 + h) * 64 + rr)) * SEQ
                                          + t0 + mi * 16] = o;
                    }
                }
            }
        }
    } else {                                  // v path -> VT[b, n, s]
        #pragma unroll
        for (int ni = 0; ni < 4; ++ni) {
            const int loc = wc * 64 + ni * 16 + (lane & 15);
            const int n = (j0 - 2048) + loc;
            const float cv = cvec[j0 + loc];
            #pragma unroll
            for (int mi = 0; mi < 4; ++mi) {
                ushort4 o = { f2b(acc[mi][ni][0] + cv), f2b(acc[mi][ni][1] + cv),
                              f2b(acc[mi][ni][2] + cv), f2b(acc[mi][ni][3] + cv) };
                *(ushort4*)&VT[((size_t)(bq * 512 + n)) * SEQ + t0 + mi * 16] = o;
            }
        }
    }
}

// ---------------- bf16 MFMA GEMM: final projection ---------------------------
// grid 1024 flat; XCD swizzle; T4 pipelined K-loop + T2 swizzle.
__global__ __launch_bounds__(256) void gemm_mfma_final(
    const unsigned short* __restrict__ Ab,
    const unsigned short* __restrict__ WTp,
    const float* __restrict__ bias, float* __restrict__ out)
{
    __shared__ __align__(16) unsigned short smem[24576];   // 48 KB
    unsigned short* sm = smem;

    const int tid = threadIdx.x;
    const int w = tid >> 6, lane = tid & 63;
    const int flat = blockIdx.x;
    const int xcd = flat & 7, slot = flat >> 3;      // 128 slots per XCD
    const int n0 = (xcd * 32 + (slot >> 2)) * 128;
    const int j0 = (slot & 3) * 128;
    const int wr = w >> 1, wc = w & 1;

    const int r0 = w * 32 + (lane >> 2);
    const int kq = ((lane & 3) ^ ((lane >> 3) & 3)) * 8;
    const unsigned short* gA = &Ab[(size_t)(n0 + r0) * 512 + kq];
    const unsigned short* gB = &WTp[(size_t)(j0 + r0) * 512 + kq];

    f32x4 acc[4][4];
    #pragma unroll
    for (int i = 0; i < 4; ++i)
        #pragma unroll
        for (int j = 0; j < 4; ++j) { acc[i][j] = (f32x4){0.f, 0.f, 0.f, 0.f}; }

    const int cr = (((lane >> 4) ^ ((lane >> 1) & 3)) * 8);

    KLOOP_P;

    #pragma unroll
    for (int ni = 0; ni < 4; ++ni) {
        const int jcol = j0 + wc * 64 + ni * 16 + (lane & 15);
        const float bvv = bias[jcol];
        #pragma unroll
        for (int mi = 0; mi < 4; ++mi) {
            #pragma unroll
            for (int r = 0; r < 4; ++r) {
                const int t = n0 + wr * 64 + mi * 16 + (lane >> 4) * 4 + r;
                out[(size_t)t * 512 + jcol] = acc[mi][ni][r] + bvv;
            }
        }
    }
}

// ---------------- kv = phi_k^T @ v via MFMA, split-K over 32 segments --------
// Coalesced LDS staging (rows are 512B contiguous): per 64-K step, A 8KB +
// B 8KB staged via 4 cp16/wave (1KB each, fully coalesced). 3-buffer
// counted-vmcnt loop (r13 shape). Fragment reads XOR-chunk-swizzled
// (c ^ (row&7), 128B rows) -> structural-floor LDS access; source
// pre-swizzled per rule #21 (within-row chunk permutation keeps the
// global reads line-coalesced).
__global__ __launch_bounds__(256) void kv_mfma(
    const unsigned short* __restrict__ PHIKT, const unsigned short* __restrict__ VT,
    float* __restrict__ KVP, float* __restrict__ KSP)
{
    __shared__ __align__(16) unsigned short smem[24576];   // 48 KB: 3 x (A|B)
    unsigned short* sm = smem;
    const int bh = blockIdx.x, seg = blockIdx.y;
    const int tid = threadIdx.x;
    const int w = tid >> 6, lane = tid & 63;

    // staging addresses: wave w stages A rows w*16..+15 and B rows w*16..+15
    // (2 cp16 each of 8 rows). src chunk pre-swizzle: (lane&7) ^ (row&7),
    // row = lane>>3 within the 8-row group (group base is mult of 8).
    const int srow = w * 16 + (lane >> 3);
    const int csw  = ((lane & 7) ^ ((lane >> 3) & 7)) * 8;
    const unsigned short* gA0 = &PHIKT[(size_t)(bh * 64 + srow) * SEQ + seg * 256 + csw];
    const unsigned short* gA1 = gA0 + (size_t)8 * SEQ;
    const int vb = (bh >> 3) * 512 + (bh & 7) * 64;
    const unsigned short* gB0 = &VT[(size_t)(vb + srow) * SEQ + seg * 256 + csw];
    const unsigned short* gB1 = gB0 + (size_t)8 * SEQ;

#define STAGE_KV(t, off)                                                        \
    do {                                                                        \
        unsigned short* dA = sm + (off) + (w * 16) * 64;                        \
        cp16(gA0 + (t) * 64, dA);                                               \
        cp16(gA1 + (t) * 64, dA + 512);                                         \
        unsigned short* dB = sm + (off) + 4096 + (w * 16) * 64;                 \
        cp16(gB0 + (t) * 64, dB);                                               \
        cp16(gB1 + (t) * 64, dB + 512);                                         \
    } while (0)

    f32x4 acc[4], ksa;
    #pragma unroll
    for (int nt = 0; nt < 4; ++nt) acc[nt] = (f32x4){0.f, 0.f, 0.f, 0.f};
    ksa = (f32x4){0.f, 0.f, 0.f, 0.f};
    bf16x8 ones;
    #pragma unroll
    for (int i = 0; i < 8; ++i) ones[i] = (short)0x3f80;   // bf16 1.0

    STAGE_KV(0, 0u);
    STAGE_KV(1, 8192u);
    unsigned o0 = 0u, o1 = 8192u, o2 = 16384u;
    #pragma unroll 1
    for (int t = 0; t < 4; ++t) {
        SBAR;
        if (t < 2)       { STAGE_KV(t + 2, o2); WAITV(8); }
        else if (t == 2) { WAITV(4); }
        else             { WAITV(0); }
        SBAR;
        __builtin_amdgcn_s_setprio(1);
        #pragma unroll
        for (int ks = 0; ks < 2; ++ks) {
            const int cks = ((ks * 4 + (lane >> 4)) ^ (lane & 7)) * 8;
            bf16x8 a = *(const bf16x8*)&sm[o0 + (w * 16 + (lane & 15)) * 64 + cks];
            ksa = __builtin_amdgcn_mfma_f32_16x16x32_bf16(a, ones, ksa, 0, 0, 0);
            #pragma unroll
            for (int nt = 0; nt < 4; ++nt) {
                bf16x8 bb = *(const bf16x8*)&sm[o0 + 4096 + (nt * 16 + (lane & 15)) * 64 + cks];
                acc[nt] = __builtin_amdgcn_mfma_f32_16x16x32_bf16(a, bb, acc[nt], 0, 0, 0);
            }
        }
        __builtin_amdgcn_s_setprio(0);
        unsigned tmp = o0; o0 = o1; o1 = o2; o2 = tmp;
    }

    // D layout: col(lane&15)=d-within-tile, row=(lane>>4)*4+reg = r-within-tile
    float* kvp = &KVP[((size_t)bh * 32 + seg) * 4096];
    #pragma unroll
    for (int nt = 0; nt < 4; ++nt) {
        float4 o = { acc[nt][0], acc[nt][1], acc[nt][2], acc[nt][3] };
        *(float4*)&kvp[(nt * 16 + (lane & 15)) * 64 + w * 16 + (lane >> 4) * 4] = o;
    }
    if ((lane & 15) == 0) {
        float4 o = { ksa[0], ksa[1], ksa[2], ksa[3] };
        *(float4*)&KSP[((size_t)bh * 32 + seg) * 64 + w * 16 + (lane >> 4) * 4] = o;
    }
}

__global__ __launch_bounds__(256) void kv_reduce(
    const float* __restrict__ KVP, const float* __restrict__ KSP,
    float* __restrict__ KV, float* __restrict__ KS)
{
    const int bh = blockIdx.x;
    const int e0 = blockIdx.y * 512;
    for (int e = e0 + threadIdx.x; e < e0 + 512; e += 256) {
        float s = 0.f;
        #pragma unroll 8
        for (int c = 0; c < 32; ++c) s += KVP[(size_t)(bh * 32 + c) * 4096 + e];
        KV[(size_t)bh * 4096 + e] = s;
    }
    if (blockIdx.y == 0 && threadIdx.x < 64) {
        float s = 0.f;
        for (int c = 0; c < 32; ++c) s += KSP[(bh * 32 + c) * 64 + threadIdx.x];
        KS[bh * 64 + threadIdx.x] = s;
    }
}

// ---------------- out_attn = (phi_q@KV)/(phi_q@ksum+eps) via MFMA ------------
// bpad reused after fragment loads as per-wave output bounce -> OAb stores
// are 64B-coalesced uint4 (were 64x scattered 2B per wave).
__global__ __launch_bounds__(256) void attn_mfma(
    const unsigned short* __restrict__ PHIQ, const float* __restrict__ KV,
    const float* __restrict__ KS, unsigned short* __restrict__ OAb)
{
    __shared__ __align__(16) unsigned short bpad[144 * 72];
    const int bh = blockIdx.x, st = blockIdx.y;
    const int tid = threadIdx.x;
    const int b = bh >> 3, h = bh & 7;

    for (int i = tid; i < 144 * 64; i += 256) {
        const int n = i >> 6, r = i & 63;
        float val;
        if (n < 64)        val = KV[(size_t)bh * 4096 + n * 64 + r];
        else if (n < 128)  { float x = KV[(size_t)bh * 4096 + (n - 64) * 64 + r];
                             val = x - b2f(f2b(x)); }
        else if (n == 128) val = KS[bh * 64 + r];
        else if (n == 129) { float x = KS[bh * 64 + r]; val = x - b2f(f2b(x)); }
        else               val = 0.f;
        bpad[n * 72 + r] = f2b(val);
    }
    __syncthreads();

    const int w = tid >> 6, lane = tid & 63;
    bf16x8 bf[9][2];
    #pragma unroll
    for (int nt = 0; nt < 9; ++nt) {
        const unsigned short* bp = &bpad[(nt * 16 + (lane & 15)) * 72 + (lane >> 4) * 8];
        bf[nt][0] = *(const bf16x8*)bp;
        bf[nt][1] = *(const bf16x8*)(bp + 32);
    }
    __syncthreads();                       // all waves done reading bpad
    unsigned short* ob = bpad + w * 1152;  // per-wave bounce: 16 rows x 72

    const int tw = st * 256 + w * 64;
    #pragma unroll
    for (int mt = 0; mt < 4; ++mt) {
        const unsigned short* ap =
            &PHIQ[((size_t)bh * SEQ + tw + mt * 16 + (lane & 15)) * 64 + (lane >> 4) * 8];
        bf16x8 a0 = *(const bf16x8*)ap;
        bf16x8 a1 = *(const bf16x8*)(ap + 32);
        f32x4 acc[9];
        #pragma unroll
        for (int nt = 0; nt < 9; ++nt) acc[nt] = (f32x4){0.f, 0.f, 0.f, 0.f};
        #pragma unroll
        for (int nt = 0; nt < 9; ++nt) {
            acc[nt] = __builtin_amdgcn_mfma_f32_16x16x32_bf16(a0, bf[nt][0], acc[nt], 0, 0, 0);
            acc[nt] = __builtin_amdgcn_mfma_f32_16x16x32_bf16(a1, bf[nt][1], acc[nt], 0, 0, 0);
        }
        #pragma unroll
        for (int r4 = 0; r4 < 4; ++r4) {
            const float den = __shfl(acc[8][r4], (lane & 48)) +
                              __shfl(acc[8][r4], (lane & 48) + 1) + 1e-6f;
            const float inv = 1.0f / den;
            const int rl = (lane >> 4) * 4 + r4;       // local row 0..15
            #pragma unroll
            for (int nt = 0; nt < 4; ++nt)
                ob[rl * 72 + nt * 16 + (lane & 15)] =
                    f2b((acc[nt][r4] + acc[nt + 4][r4]) * inv);
        }
        // wave-local coalesced readback + store (compiler orders LDS deps)
        #pragma unroll
        for (int p = 0; p < 2; ++p) {
            const int rl = lane >> 2;
            const int sl = (lane & 3) + p * 4;
            uint4 v = *(const uint4*)&ob[rl * 72 + sl * 8];
            const int s = tw + mt * 16 + rl;
            *(uint4*)&OAb[((size_t)b * SEQ + s) * 512 + h * 64 + sl * 8] = v;
        }
    }
}

extern "C" void kernel_launch(void* const* d_in, const int* in_sizes, int n_in,
                              void* d_out, int out_size, void* d_ws, size_t ws_size,
                              hipStream_t stream)
{
    (void)in_sizes; (void)n_in; (void)out_size; (void)ws_size;
    const float* x   = (const float*)d_in[0];
    const float* Wq  = (const float*)d_in[1];
    const float* bq  = (const float*)d_in[2];
    const float* Wk  = (const float*)d_in[3];
    const float* bk  = (const float*)d_in[4];
    const float* Wv  = (const float*)d_in[5];
    const float* bv  = (const float*)d_in[6];
    const float* Wp  = (const float*)d_in[7];
    const float* bp  = (const float*)d_in[8];
    const float* gq  = (const float*)d_in[9];
    const float* bbq = (const float*)d_in[10];
    const float* gk  = (const float*)d_in[11];
    const float* bbk = (const float*)d_in[12];
    const float* qG1 = (const float*)d_in[13];
    const float* qG2 = (const float*)d_in[14];
    const float* kG1 = (const float*)d_in[15];
    const float* kG2 = (const float*)d_in[16];

    unsigned short* PHIQ  = (unsigned short*)d_ws;      // 32 MB [b,h,s,r]
    unsigned short* PHIKT = PHIQ + 16777216;            // 32 MB [b,h,r,s]
    unsigned short* VT    = PHIKT + 16777216;           // 32 MB [b,h*64+d,s]
    unsigned short* xb    = VT   + 16777216;            // 32 MB
    unsigned short* OAb   = xb   + 16777216;            // 32 MB
    unsigned short* WTf   = OAb  + 16777216;            // 2.5 MB
    unsigned short* WTp   = WTf  + 2560 * 512;          // 0.5 MB
    float* cvec = (float*)(WTp + 262144);               // 2,560 f
    float* KVP  = cvec + 2560;                          // 16 MB [bh,seg32][d][r]
    float* KSP  = KVP + 4194304;                        // 256 KB
    float* KV   = KSP + 65536;                          // 512 KB [bh][d][r]
    float* KS   = KV + 131072;                          // 8 KB
    float* out  = (float*)d_out;

    hipLaunchKernelGGL(prep_all, dim3(9217), dim3(256), 0, stream,
                       x, xb, Wv, Wp, WTf, WTp,
                       Wq, bq, Wk, bk, bv, gq, bbq, gk, bbk,
                       qG1, qG2, kG1, kG2, cvec);
    hipLaunchKernelGGL(gemm_mfma_fused, dim3(5120), dim3(256), 0, stream,
                       xb, WTf, cvec, PHIQ, PHIKT, VT);
    hipLaunchKernelGGL(kv_mfma, dim3(32, 32), dim3(256), 0, stream,
                       PHIKT, VT, KVP, KSP);
    hipLaunchKernelGGL(kv_reduce, dim3(32, 8), dim3(256), 0, stream, KVP, KSP, KV, KS);
    hipLaunchKernelGGL(attn_mfma, dim3(32, 32), dim3(256), 0, stream,
                       PHIQ, KV, KS, OAb);
    hipLaunchKernelGGL(gemm_mfma_final, dim3(1024), dim3(256), 0, stream,
                       OAb, WTp, bp, out);
}